// Round 1
// baseline (1007.293 us; speedup 1.0000x reference)
//
#include <hip/hip_runtime.h>
#include <math.h>

// ---------------------------------------------------------------------------
// EquivariantCorrectionHead: B=131072, NS=64, H=32
// Strategy: fold all scale constants + symmetrize weights in a prep kernel,
// then one lane per batch element, h in registers, s staged in LDS,
// weights read via wave-uniform scalar loads.
// ---------------------------------------------------------------------------

#define NPAIR64 2080  // 64*65/2

// Preprocessed weight tables (rewritten identically on every call)
__device__ float g_wsss[NPAIR64 * 32];  // [pair(u<=v)][w], includes PW1_0 and sym-fold
__device__ float g_wst [64 * 5 * 32];   // [u][v][w] combined stt+tst, incl PW1_2*IS5
__device__ float g_wtts[15 * 32];       // [pair5][w], incl PW1_0*IS5 and sym-fold
__device__ float g_wttt[15 * 32];       // [pair5][w], incl PW1_2 and sym-fold
__device__ float g_w2c [32 * 32];       // [v][u] combined w2_stt+w2_tst, incl PW2_2*IS5
__device__ float g_w2t [32 * 32];       // [v][u] transposed w2_ttt, incl PW2_2

__device__ const int d_pu5[15] = {0,0,0,0,0,1,1,1,1,2,2,2,3,3,4};
__device__ const int d_pv5[15] = {0,1,2,3,4,1,2,3,4,2,3,4,3,4,4};

__global__ void prep_kernel(const float* __restrict__ w1_sss,
                            const float* __restrict__ w1_stt,
                            const float* __restrict__ w1_tst,
                            const float* __restrict__ w1_tts,
                            const float* __restrict__ w1_ttt,
                            const float* __restrict__ w2_stt,
                            const float* __restrict__ w2_tst,
                            const float* __restrict__ w2_ttt) {
  const float PW1_0 = (float)(1.0 / sqrt(4121.0));       // (NS^2+25)^-1/2
  const float PW1_2 = (float)sqrt(5.0 / 665.0);          // (5/(10*NS+25))^1/2
  const float PW2_2 = (float)sqrt(5.0 / 3072.0);         // (5/(3*H^2))^1/2
  const float IS5   = (float)sqrt(0.2);                  // 5^-1/2

  int idx = blockIdx.x * blockDim.x + threadIdx.x;

  // region 0: symmetrized sss weights, index space 64*64*32
  if (idx < 64 * 64 * 32) {
    int w = idx & 31, v = (idx >> 5) & 63, u = idx >> 11;
    if (u <= v) {
      float val = w1_sss[(u * 64 + v) * 32 + w];
      if (u < v) val += w1_sss[(v * 64 + u) * 32 + w];
      int p = u * (129 - u) / 2 + (v - u);
      g_wsss[p * 32 + w] = val * PW1_0;
    }
    return;
  }
  idx -= 64 * 64 * 32;

  // region 1: combined stt+tst, 64*5*32
  if (idx < 64 * 5 * 32) {
    int w = idx & 31, v = (idx >> 5) % 5, u = idx / 160;
    g_wst[idx] = (w1_stt[(u * 5 + v) * 32 + w] + w1_tst[(v * 64 + u) * 32 + w]) * (PW1_2 * IS5);
    return;
  }
  idx -= 64 * 5 * 32;

  // region 2: symmetrized tts pairs, 15*32
  if (idx < 15 * 32) {
    int w = idx & 31, p = idx >> 5;
    int u = d_pu5[p], v = d_pv5[p];
    float val = w1_tts[(u * 5 + v) * 32 + w];
    if (u < v) val += w1_tts[(v * 5 + u) * 32 + w];
    g_wtts[idx] = val * (PW1_0 * IS5);
    return;
  }
  idx -= 15 * 32;

  // region 3: symmetrized ttt pairs, 15*32
  if (idx < 15 * 32) {
    int w = idx & 31, p = idx >> 5;
    int u = d_pu5[p], v = d_pv5[p];
    float val = w1_ttt[(u * 5 + v) * 32 + w];
    if (u < v) val += w1_ttt[(v * 5 + u) * 32 + w];
    g_wttt[idx] = val * PW1_2;
    return;
  }
  idx -= 15 * 32;

  // region 4: tp2 combined stt+tst weights, stored [v][u]
  if (idx < 1024) {
    int v = idx >> 5, u = idx & 31;
    g_w2c[idx] = (w2_stt[u * 32 + v] + w2_tst[v * 32 + u]) * (PW2_2 * IS5);
    return;
  }
  idx -= 1024;

  // region 5: tp2 ttt weights, stored [v][u]
  if (idx < 1024) {
    int v = idx >> 5, u = idx & 31;
    g_w2t[idx] = w2_ttt[u * 32 + v] * PW2_2;
    return;
  }
}

// Wigner C222 (derived analytically; Frobenius-normalized):
// nonzero fully-symmetric entries:
//  (0,0,2) = -sqrt(2/35)   (0,1,3) = +sqrt(3/70)   (1,1,2) = +sqrt(1/70)
//  (1,1,4) = -sqrt(3/70)   (2,2,2) = +sqrt(2/35)   (2,3,3) = +sqrt(1/70)
//  (2,4,4) = -sqrt(2/35)   (3,3,4) = +sqrt(3/70)
#define CW1 0.23904572186687872f  // sqrt(2/35)
#define CW2 0.20701966780270626f  // sqrt(3/70)
#define CW3 0.11952286093343936f  // sqrt(1/70)

__global__ __launch_bounds__(64)
void ech_main(const float* __restrict__ scalars,
              const float* __restrict__ tk, const float* __restrict__ tm,
              const float* __restrict__ tc, const float* __restrict__ tb,
              const float* __restrict__ tmc,
              float* __restrict__ out) {
  __shared__ float sld[64][65];
  const int lane = threadIdx.x;
  const int b0 = blockIdx.x * 64;
  const int b = b0 + lane;

  // cooperative, coalesced stage of the 64x64 scalars tile
  for (int r = 0; r < 64; ++r)
    sld[r][lane] = scalars[(b0 + r) * 64 + lane];
  __syncthreads();

  // t[j][i]: j = which tensor input (mul index u), i = m component
  float t[5][5];
#pragma unroll
  for (int i = 0; i < 5; ++i) t[0][i] = tk [b * 5 + i];
#pragma unroll
  for (int i = 0; i < 5; ++i) t[1][i] = tm [b * 5 + i];
#pragma unroll
  for (int i = 0; i < 5; ++i) t[2][i] = tc [b * 5 + i];
#pragma unroll
  for (int i = 0; i < 5; ++i) t[3][i] = tb [b * 5 + i];
#pragma unroll
  for (int i = 0; i < 5; ++i) t[4][i] = tmc[b * 5 + i];

  float hs[32];
  float ht[32][5];
#pragma unroll
  for (int w = 0; w < 32; ++w) {
    hs[w] = 0.f;
#pragma unroll
    for (int k = 0; k < 5; ++k) ht[w][k] = 0.f;
  }

  // ---------------- tp1: sss (dominant) ----------------
  {
    const float* wp = g_wsss;
    for (int u = 0; u < 64; ++u) {
      const float su = sld[lane][u];
      for (int v = u; v < 64; ++v) {
        const float prod = su * sld[lane][v];
#pragma unroll
        for (int w = 0; w < 32; ++w)
          hs[w] = fmaf(wp[w], prod, hs[w]);
        wp += 32;
      }
    }
  }

  // ---------------- tp1: tts ----------------
  {
    constexpr int pu[15] = {0,0,0,0,0,1,1,1,1,2,2,2,3,3,4};
    constexpr int pv[15] = {0,1,2,3,4,1,2,3,4,2,3,4,3,4,4};
#pragma unroll
    for (int p = 0; p < 15; ++p) {
      const int u = pu[p], v = pv[p];
      float d = 0.f;
#pragma unroll
      for (int i = 0; i < 5; ++i) d = fmaf(t[u][i], t[v][i], d);
#pragma unroll
      for (int w = 0; w < 32; ++w)
        hs[w] = fmaf(g_wtts[p * 32 + w], d, hs[w]);
    }
  }

  // ---------------- tp1: stt + tst (combined) ----------------
#pragma unroll
  for (int wc = 0; wc < 8; ++wc) {  // w in chunks of 4
    float a[5][4];
#pragma unroll
    for (int v = 0; v < 5; ++v)
#pragma unroll
      for (int q = 0; q < 4; ++q) a[v][q] = 0.f;
    for (int u = 0; u < 64; ++u) {
      const float su = sld[lane][u];
      const float* wq = g_wst + u * 160 + wc * 4;
#pragma unroll
      for (int v = 0; v < 5; ++v)
#pragma unroll
        for (int q = 0; q < 4; ++q)
          a[v][q] = fmaf(wq[v * 32 + q], su, a[v][q]);
    }
#pragma unroll
    for (int v = 0; v < 5; ++v)
#pragma unroll
      for (int q = 0; q < 4; ++q)
#pragma unroll
        for (int k = 0; k < 5; ++k)
          ht[wc * 4 + q][k] = fmaf(a[v][q], t[v][k], ht[wc * 4 + q][k]);
  }

  // ---------------- tp1: ttt ----------------
  {
    constexpr int pu[15] = {0,0,0,0,0,1,1,1,1,2,2,2,3,3,4};
    constexpr int pv[15] = {0,1,2,3,4,1,2,3,4,2,3,4,3,4,4};
#pragma unroll
    for (int p = 0; p < 15; ++p) {
      const int u = pu[p], v = pv[p];
      const float d0 = t[u][0] * t[v][0];
      const float d1 = t[u][1] * t[v][1];
      const float d2 = t[u][2] * t[v][2];
      const float d3 = t[u][3] * t[v][3];
      const float d4 = t[u][4] * t[v][4];
      const float s01 = t[u][0] * t[v][1] + t[u][1] * t[v][0];
      const float s02 = t[u][0] * t[v][2] + t[u][2] * t[v][0];
      const float s03 = t[u][0] * t[v][3] + t[u][3] * t[v][0];
      const float s12 = t[u][1] * t[v][2] + t[u][2] * t[v][1];
      const float s13 = t[u][1] * t[v][3] + t[u][3] * t[v][1];
      const float s14 = t[u][1] * t[v][4] + t[u][4] * t[v][1];
      const float s23 = t[u][2] * t[v][3] + t[u][3] * t[v][2];
      const float s24 = t[u][2] * t[v][4] + t[u][4] * t[v][2];
      const float s34 = t[u][3] * t[v][4] + t[u][4] * t[v][3];
      const float E0 = -CW1 * s02 + CW2 * s13;
      const float E1 =  CW2 * s03 + CW3 * s12 - CW2 * s14;
      const float E2 = -CW1 * d0 + CW3 * d1 + CW1 * d2 + CW3 * d3 - CW1 * d4;
      const float E3 =  CW2 * s01 + CW3 * s23 + CW2 * s34;
      const float E4 = -CW2 * d1 - CW1 * s24 + CW2 * d3;
#pragma unroll
      for (int w = 0; w < 32; ++w) {
        const float wv = g_wttt[p * 32 + w];
        ht[w][0] = fmaf(wv, E0, ht[w][0]);
        ht[w][1] = fmaf(wv, E1, ht[w][1]);
        ht[w][2] = fmaf(wv, E2, ht[w][2]);
        ht[w][3] = fmaf(wv, E3, ht[w][3]);
        ht[w][4] = fmaf(wv, E4, ht[w][4]);
      }
    }
  }

  // ---------------- tp2 ----------------
  float o0 = 0.f, o1 = 0.f, o2 = 0.f, o3 = 0.f, o4 = 0.f;

  // stt + tst combined: out[k] += sum_v (sum_u w2c[v][u] hs[u]) * ht[v][k]
#pragma unroll
  for (int v = 0; v < 32; ++v) {
    float acc = 0.f;
#pragma unroll
    for (int u = 0; u < 32; ++u) acc = fmaf(g_w2c[v * 32 + u], hs[u], acc);
    o0 = fmaf(acc, ht[v][0], o0);
    o1 = fmaf(acc, ht[v][1], o1);
    o2 = fmaf(acc, ht[v][2], o2);
    o3 = fmaf(acc, ht[v][3], o3);
    o4 = fmaf(acc, ht[v][4], o4);
  }

  // ttt: Q[i][j] = sum_v g[v][i] * ht[v][j], g[v][i] = sum_u w2t[v][u] ht[u][i]
  float Q[5][5];
#pragma unroll
  for (int i = 0; i < 5; ++i)
#pragma unroll
    for (int j = 0; j < 5; ++j) Q[i][j] = 0.f;
#pragma unroll
  for (int v = 0; v < 32; ++v) {
    float g0 = 0.f, g1 = 0.f, g2 = 0.f, g3 = 0.f, g4 = 0.f;
#pragma unroll
    for (int u = 0; u < 32; ++u) {
      const float wv = g_w2t[v * 32 + u];
      g0 = fmaf(wv, ht[u][0], g0);
      g1 = fmaf(wv, ht[u][1], g1);
      g2 = fmaf(wv, ht[u][2], g2);
      g3 = fmaf(wv, ht[u][3], g3);
      g4 = fmaf(wv, ht[u][4], g4);
    }
#pragma unroll
    for (int j = 0; j < 5; ++j) {
      Q[0][j] = fmaf(g0, ht[v][j], Q[0][j]);
      Q[1][j] = fmaf(g1, ht[v][j], Q[1][j]);
      Q[2][j] = fmaf(g2, ht[v][j], Q[2][j]);
      Q[3][j] = fmaf(g3, ht[v][j], Q[3][j]);
      Q[4][j] = fmaf(g4, ht[v][j], Q[4][j]);
    }
  }

  const float Qs01 = Q[0][1] + Q[1][0], Qs02 = Q[0][2] + Q[2][0];
  const float Qs03 = Q[0][3] + Q[3][0], Qs12 = Q[1][2] + Q[2][1];
  const float Qs13 = Q[1][3] + Q[3][1], Qs14 = Q[1][4] + Q[4][1];
  const float Qs23 = Q[2][3] + Q[3][2], Qs24 = Q[2][4] + Q[4][2];
  const float Qs34 = Q[3][4] + Q[4][3];

  o0 += -CW1 * Qs02 + CW2 * Qs13;
  o1 +=  CW2 * Qs03 + CW3 * Qs12 - CW2 * Qs14;
  o2 += -CW1 * Q[0][0] + CW3 * Q[1][1] + CW1 * Q[2][2] + CW3 * Q[3][3] - CW1 * Q[4][4];
  o3 +=  CW2 * Qs01 + CW3 * Qs23 + CW2 * Qs34;
  o4 += -CW2 * Q[1][1] - CW1 * Qs24 + CW2 * Q[3][3];

  out[b * 5 + 0] = o0;
  out[b * 5 + 1] = o1;
  out[b * 5 + 2] = o2;
  out[b * 5 + 3] = o3;
  out[b * 5 + 4] = o4;
}

extern "C" void kernel_launch(void* const* d_in, const int* in_sizes, int n_in,
                              void* d_out, int out_size, void* d_ws, size_t ws_size,
                              hipStream_t stream) {
  (void)n_in; (void)out_size; (void)d_ws; (void)ws_size;
  const float* scalars = (const float*)d_in[0];
  const float* tk  = (const float*)d_in[1];
  const float* tm  = (const float*)d_in[2];
  const float* tc  = (const float*)d_in[3];
  const float* tb  = (const float*)d_in[4];
  const float* tmc = (const float*)d_in[5];
  const float* w1_sss = (const float*)d_in[6];
  const float* w1_stt = (const float*)d_in[7];
  const float* w1_tst = (const float*)d_in[8];
  const float* w1_tts = (const float*)d_in[9];
  const float* w1_ttt = (const float*)d_in[10];
  const float* w2_stt = (const float*)d_in[11];
  const float* w2_tst = (const float*)d_in[12];
  const float* w2_ttt = (const float*)d_in[13];
  float* out = (float*)d_out;

  const int B = in_sizes[0] / 64;

  const int prep_total = 64 * 64 * 32 + 64 * 5 * 32 + 15 * 32 + 15 * 32 + 1024 + 1024;
  prep_kernel<<<(prep_total + 255) / 256, 256, 0, stream>>>(
      w1_sss, w1_stt, w1_tst, w1_tts, w1_ttt, w2_stt, w2_tst, w2_ttt);

  ech_main<<<B / 64, 64, 0, stream>>>(scalars, tk, tm, tc, tb, tmc, out);
}

// Round 4
// 164.217 us; speedup vs baseline: 6.1339x; 6.1339x over previous
//
#include <hip/hip_runtime.h>
#include <math.h>
#include <stdint.h>

// ---------------------------------------------------------------------------
// EquivariantCorrectionHead, MFMA formulation v3 (UB-free).
// B=131072, NS=64, H=32. Block = 256 thr (4 waves), 128 batch rows/block.
// ALL LDS traffic is uint32 through one array (no mixed-type aliasing).
// No unions: fragments built via __builtin_bit_cast / direct bf16x8 loads.
// ---------------------------------------------------------------------------

#define CW1 0.23904572186687872f  // sqrt(2/35)
#define CW2 0.20701966780270626f  // sqrt(3/70)
#define CW3 0.11952286093343936f  // sqrt(1/70)

typedef float f32x16 __attribute__((ext_vector_type(16)));
typedef short bf16x8 __attribute__((ext_vector_type(8)));
typedef uint32_t u32x4 __attribute__((ext_vector_type(4)));

__device__ __forceinline__ uint32_t f2bf(float f) {  // RNE float->bf16
  uint32_t x = __float_as_uint(f);
  return (x + 0x7fffu + ((x >> 16) & 1u)) >> 16;
}
__device__ __forceinline__ uint32_t packbf(float lo, float hi) {
  return f2bf(lo) | (f2bf(hi) << 16);
}
__device__ __forceinline__ float bflo(uint32_t d) { return __uint_as_float(d << 16); }
__device__ __forceinline__ float bfhi(uint32_t d) { return __uint_as_float(d & 0xffff0000u); }

__device__ __forceinline__ f32x16 zero16() {
  f32x16 z;
#pragma unroll
  for (int i = 0; i < 16; ++i) z[i] = 0.f;
  return z;
}

#define MFMA(a, b, c) __builtin_amdgcn_mfma_f32_32x32x16_bf16((a), (b), (c), 0, 0, 0)

// Pre-swizzled bf16 B-fragment tables (dword = 2 packed bf16: k, k+1).
// Fragment convention: lane l (h=l>>5, col=l&31), dword d holds k=base+8h+2d, +1.
__device__ __align__(16) uint32_t g_bsss[64 * 4 * 64 * 4];  // [v][c][l][d], k=u (K=64)
__device__ __align__(16) uint32_t g_bst[5 * 4 * 64 * 4];    // [v][c][l][d], k=u (K=64)
__device__ __align__(16) uint32_t g_btts[64 * 4];           // [l][d], k=p (K=16, p15 pad)
__device__ __align__(16) uint32_t g_bttt[64 * 4];           // [l][d]
__device__ __align__(16) uint32_t g_bg2[2 * 64 * 4];        // [c][l][d], k=u (K=32)
__device__ __align__(16) uint32_t g_bgt[2 * 64 * 4];        // [c][l][d]

__device__ const int c_pu[16] = {0,0,0,0,0,1,1,1,1,2,2,2,3,3,4,0};
__device__ const int c_pv[16] = {0,1,2,3,4,1,2,3,4,2,3,4,3,4,4,0};

__global__ void ech_prep(const float* __restrict__ w1_sss, const float* __restrict__ w1_stt,
                         const float* __restrict__ w1_tst, const float* __restrict__ w1_tts,
                         const float* __restrict__ w1_ttt, const float* __restrict__ w2_stt,
                         const float* __restrict__ w2_tst, const float* __restrict__ w2_ttt) {
  const float PW1_0 = (float)(1.0 / sqrt(4121.0));
  const float PW1_2 = (float)sqrt(5.0 / 665.0);
  const float PW2_2 = (float)sqrt(5.0 / 3072.0);
  const float IS5   = (float)sqrt(0.2);

  int idx = blockIdx.x * 256 + threadIdx.x;

  if (idx < 65536) {  // g_bsss
    int d = idx & 3, l = (idx >> 2) & 63, c = (idx >> 8) & 3, v = idx >> 10;
    int h = l >> 5, w = l & 31;
    int u0 = c * 16 + 8 * h + 2 * d;
    g_bsss[idx] = packbf(PW1_0 * w1_sss[(u0 * 64 + v) * 32 + w],
                         PW1_0 * w1_sss[((u0 + 1) * 64 + v) * 32 + w]);
    return;
  }
  idx -= 65536;
  if (idx < 5120) {  // g_bst
    int d = idx & 3, l = (idx >> 2) & 63, c = (idx >> 8) & 3, v = idx >> 10;
    int h = l >> 5, w = l & 31;
    float sc = PW1_2 * IS5;
    int u0 = c * 16 + 8 * h + 2 * d, u1 = u0 + 1;
    g_bst[idx] = packbf(sc * (w1_stt[(u0 * 5 + v) * 32 + w] + w1_tst[(v * 64 + u0) * 32 + w]),
                        sc * (w1_stt[(u1 * 5 + v) * 32 + w] + w1_tst[(v * 64 + u1) * 32 + w]));
    return;
  }
  idx -= 5120;
  if (idx < 256) {  // g_btts
    int d = idx & 3, l = idx >> 2;
    int h = l >> 5, w = l & 31;
    float sc = PW1_0 * IS5;
    float val[2];
#pragma unroll
    for (int q = 0; q < 2; ++q) {
      int p = 8 * h + 2 * d + q;
      float x = 0.f;
      if (p < 15) {
        int u = c_pu[p], v = c_pv[p];
        x = w1_tts[(u * 5 + v) * 32 + w];
        if (u < v) x += w1_tts[(v * 5 + u) * 32 + w];
        x *= sc;
      }
      val[q] = x;
    }
    g_btts[idx] = packbf(val[0], val[1]);
    return;
  }
  idx -= 256;
  if (idx < 256) {  // g_bttt
    int d = idx & 3, l = idx >> 2;
    int h = l >> 5, w = l & 31;
    float val[2];
#pragma unroll
    for (int q = 0; q < 2; ++q) {
      int p = 8 * h + 2 * d + q;
      float x = 0.f;
      if (p < 15) {
        int u = c_pu[p], v = c_pv[p];
        x = w1_ttt[(u * 5 + v) * 32 + w];
        if (u < v) x += w1_ttt[(v * 5 + u) * 32 + w];
        x *= PW1_2;
      }
      val[q] = x;
    }
    g_bttt[idx] = packbf(val[0], val[1]);
    return;
  }
  idx -= 256;
  if (idx < 512) {  // g_bg2: B[u][v] = (w2_stt[u,v]+w2_tst[v,u])*PW2_2*IS5
    int d = idx & 3, l = (idx >> 2) & 63, c = idx >> 8;
    int h = l >> 5, v = l & 31;
    float sc = PW2_2 * IS5;
    int u0 = c * 16 + 8 * h + 2 * d, u1 = u0 + 1;
    g_bg2[idx] = packbf(sc * (w2_stt[u0 * 32 + v] + w2_tst[v * 32 + u0]),
                        sc * (w2_stt[u1 * 32 + v] + w2_tst[v * 32 + u1]));
    return;
  }
  idx -= 512;
  if (idx < 512) {  // g_bgt: B[u][v] = w2_ttt[u,v]*PW2_2
    int d = idx & 3, l = (idx >> 2) & 63, c = idx >> 8;
    int h = l >> 5, v = l & 31;
    int u0 = c * 16 + 8 * h + 2 * d, u1 = u0 + 1;
    g_bgt[idx] = packbf(PW2_2 * w2_ttt[u0 * 32 + v], PW2_2 * w2_ttt[u1 * 32 + v]);
    return;
  }
}

// LDS layout (dwords), total 13568 dw = 54272 B:
//   s_packed bf16 [128][33]  @ 0      (dw 32 of each row = pad, never read)
//   t f32-bits    [128][25]  @ 4224
//   E/d bf16      [128][48]  @ 7424   (dword j of comp k at k*8+j; d at 40+j)
// After the pack barrier (s/t/Ed dead): bf16 packs [128][17] per plane:
//   hs @ 0, ht_k @ 2176*(k+1), k=0..4 (ends 13056 <= 13568)
#define OFF_T 4224
#define OFF_ED 7424
#define LDS_DW 13568

#define ROWP(r) (((r) & 3) + 8 * ((r) >> 2) + 4 * h)

__global__ __launch_bounds__(256, 1)
void ech_fused(const float* __restrict__ scalars,
               const float* __restrict__ tk, const float* __restrict__ tm,
               const float* __restrict__ tc, const float* __restrict__ tb,
               const float* __restrict__ tmc,
               float* __restrict__ out) {
  __shared__ uint32_t lds[LDS_DW];

  const int tid = threadIdx.x;
  const int rows128 = blockIdx.x * 128;
  const int wave = tid >> 6, lane = tid & 63;
  const int h = lane >> 5, wl = lane & 31;
  const int wrow = wave * 32;

  // ---- stage s (bf16-packed dwords) ----
#pragma unroll
  for (int it = 0; it < 16; ++it) {
    int di = it * 256 + tid;  // 4096 dwords
    int row = di >> 5, dw = di & 31;
    float f0 = scalars[(rows128 + row) * 64 + dw * 2];
    float f1 = scalars[(rows128 + row) * 64 + dw * 2 + 1];
    lds[row * 33 + dw] = packbf(f0, f1);
  }
  // ---- stage t (f32 bits as uint32) ----
#pragma unroll
  for (int v = 0; v < 5; ++v) {
    const float* p = (v == 0 ? tk : v == 1 ? tm : v == 2 ? tc : v == 3 ? tb : tmc);
#pragma unroll
    for (int it = 0; it < 3; ++it) {
      int i = it * 256 + tid;
      if (i < 640)
        lds[OFF_T + (i / 5) * 25 + v * 5 + (i % 5)] = __float_as_uint(p[rows128 * 5 + i]);
    }
  }
  __syncthreads();

  // ---- E/d phase: 2 threads per row, dword-granular ownership ----
  {
    int row = tid >> 1, part = tid & 1;
    float t_[5][5];
#pragma unroll
    for (int v = 0; v < 5; ++v)
#pragma unroll
      for (int k = 0; k < 5; ++k) t_[v][k] = __uint_as_float(lds[OFF_T + row * 25 + v * 5 + k]);

    float PA[6], PB[6];
#define EDP(U, V, OUT)                                                            \
  {                                                                               \
    float d0_ = t_[U][0] * t_[V][0], d1_ = t_[U][1] * t_[V][1];                   \
    float d2_ = t_[U][2] * t_[V][2], d3_ = t_[U][3] * t_[V][3];                   \
    float d4_ = t_[U][4] * t_[V][4];                                              \
    float s01_ = t_[U][0] * t_[V][1] + t_[U][1] * t_[V][0];                       \
    float s02_ = t_[U][0] * t_[V][2] + t_[U][2] * t_[V][0];                       \
    float s03_ = t_[U][0] * t_[V][3] + t_[U][3] * t_[V][0];                       \
    float s12_ = t_[U][1] * t_[V][2] + t_[U][2] * t_[V][1];                       \
    float s13_ = t_[U][1] * t_[V][3] + t_[U][3] * t_[V][1];                       \
    float s14_ = t_[U][1] * t_[V][4] + t_[U][4] * t_[V][1];                       \
    float s23_ = t_[U][2] * t_[V][3] + t_[U][3] * t_[V][2];                       \
    float s24_ = t_[U][2] * t_[V][4] + t_[U][4] * t_[V][2];                       \
    float s34_ = t_[U][3] * t_[V][4] + t_[U][4] * t_[V][3];                       \
    OUT[0] = -CW1 * s02_ + CW2 * s13_;                                            \
    OUT[1] = CW2 * s03_ + CW3 * s12_ - CW2 * s14_;                                \
    OUT[2] = -CW1 * d0_ + CW3 * d1_ + CW1 * d2_ + CW3 * d3_ - CW1 * d4_;          \
    OUT[3] = CW2 * s01_ + CW3 * s23_ + CW2 * s34_;                                \
    OUT[4] = -CW2 * d1_ - CW1 * s24_ + CW2 * d3_;                                 \
    OUT[5] = d0_ + d1_ + d2_ + d3_ + d4_;                                         \
  }
#define STEDP(j)                                                                  \
  {                                                                               \
    lds[rb + 0 * 8 + (j)] = packbf(PA[0], PB[0]);                                 \
    lds[rb + 1 * 8 + (j)] = packbf(PA[1], PB[1]);                                 \
    lds[rb + 2 * 8 + (j)] = packbf(PA[2], PB[2]);                                 \
    lds[rb + 3 * 8 + (j)] = packbf(PA[3], PB[3]);                                 \
    lds[rb + 4 * 8 + (j)] = packbf(PA[4], PB[4]);                                 \
    lds[rb + 40 + (j)] = packbf(PA[5], PB[5]);                                    \
  }
    int rb = OFF_ED + row * 48 + (part ? 4 : 0);
    if (part == 0) {
      EDP(0, 0, PA) EDP(0, 1, PB) STEDP(0)
      EDP(0, 2, PA) EDP(0, 3, PB) STEDP(1)
      EDP(0, 4, PA) EDP(1, 1, PB) STEDP(2)
      EDP(1, 2, PA) EDP(1, 3, PB) STEDP(3)
    } else {
      EDP(1, 4, PA) EDP(2, 2, PB) STEDP(0)
      EDP(2, 3, PA) EDP(2, 4, PB) STEDP(1)
      EDP(3, 3, PA) EDP(3, 4, PB) STEDP(2)
      EDP(4, 4, PA)
#pragma unroll
      for (int q = 0; q < 6; ++q) PB[q] = 0.f;
      STEDP(3)
    }
#undef EDP
#undef STEDP
  }
  __syncthreads();

  // ---- A-fragments from LDS (4 dword loads + bit_cast; no unions) ----
  bf16x8 afr[4];
#pragma unroll
  for (int c = 0; c < 4; ++c) {
    int base = (wrow + wl) * 33 + c * 8 + 4 * h;
    u32x4 tmp;
    tmp.x = lds[base]; tmp.y = lds[base + 1]; tmp.z = lds[base + 2]; tmp.w = lds[base + 3];
    afr[c] = __builtin_bit_cast(bf16x8, tmp);
  }

  // ---- GEMM1 (sss): Z_v = S @ Wsss[:,v,:], hs += s_v * Z_v (B direct-global) ----
  f32x16 hs = zero16();
  const bf16x8* gb = (const bf16x8*)g_bsss;
#pragma unroll 2
  for (int vp = 0; vp < 32; ++vp) {
    bf16x8 b0[4], b1[4];
#pragma unroll
    for (int c = 0; c < 4; ++c) {
      b0[c] = gb[(2 * vp) * 256 + c * 64 + lane];
      b1[c] = gb[(2 * vp + 1) * 256 + c * 64 + lane];
    }
    f32x16 Z0 = zero16(), Z1 = zero16();
#pragma unroll
    for (int c = 0; c < 4; ++c) {
      Z0 = MFMA(afr[c], b0[c], Z0);
      Z1 = MFMA(afr[c], b1[c], Z1);
    }
#pragma unroll
    for (int r = 0; r < 16; ++r) {
      uint32_t d = lds[(wrow + ROWP(r)) * 33 + vp];  // broadcast read
      hs[r] = fmaf(bflo(d), Z0[r], hs[r]);
      hs[r] = fmaf(bfhi(d), Z1[r], hs[r]);
    }
  }

  // ---- stt GEMM folded directly into ht ----
  f32x16 ht[5];
#pragma unroll
  for (int k = 0; k < 5; ++k) ht[k] = zero16();
  {
    const bf16x8* gs = (const bf16x8*)g_bst;
#pragma unroll
    for (int ct = 0; ct < 5; ++ct) {
      f32x16 acc = zero16();
#pragma unroll
      for (int c = 0; c < 4; ++c) acc = MFMA(afr[c], gs[(ct * 4 + c) * 64 + lane], acc);
#pragma unroll
      for (int r = 0; r < 16; ++r) {
        int row = wrow + ROWP(r);
        float av = acc[r];
#pragma unroll
        for (int k = 0; k < 5; ++k)
          ht[k][r] = fmaf(av, __uint_as_float(lds[OFF_T + row * 25 + ct * 5 + k]), ht[k][r]);
      }
    }
  }

  // ---- tts GEMM into hs ----
  {
    int base = OFF_ED + (wrow + wl) * 48 + 40 + 4 * h;
    u32x4 tmp;
    tmp.x = lds[base]; tmp.y = lds[base + 1]; tmp.z = lds[base + 2]; tmp.w = lds[base + 3];
    hs = MFMA(__builtin_bit_cast(bf16x8, tmp), ((const bf16x8*)g_btts)[lane], hs);
  }
  // ---- ttt: per-k GEMM over pair-invariants ----
  {
    bf16x8 btt = ((const bf16x8*)g_bttt)[lane];
#pragma unroll
    for (int k = 0; k < 5; ++k) {
      int base = OFF_ED + (wrow + wl) * 48 + k * 8 + 4 * h;
      u32x4 tmp;
      tmp.x = lds[base]; tmp.y = lds[base + 1]; tmp.z = lds[base + 2]; tmp.w = lds[base + 3];
      ht[k] = MFMA(__builtin_bit_cast(bf16x8, tmp), btt, ht[k]);
    }
  }

  // ---- pack hs + ht planes as bf16 dwords (shfl partner; even lanes store) ----
  __syncthreads();  // s/t/Ed regions now dead
  {
#pragma unroll
    for (int r = 0; r < 16; ++r) {
      int row = wrow + ROWP(r);
      float v0 = hs[r];
      float pv = __shfl_xor(v0, 1, 64);
      if (!(wl & 1)) lds[row * 17 + (wl >> 1)] = packbf(v0, pv);
#pragma unroll
      for (int k = 0; k < 5; ++k) {
        float w0 = ht[k][r];
        float pw = __shfl_xor(w0, 1, 64);
        if (!(wl & 1)) lds[2176 * (k + 1) + row * 17 + (wl >> 1)] = packbf(w0, pw);
      }
    }
  }
  __syncthreads();

  // ---- g2 GEMM: g2[b,v] = hs @ w2c ----
  f32x16 g2 = zero16();
#pragma unroll
  for (int c = 0; c < 2; ++c) {
    int base = (wrow + wl) * 17 + c * 8 + 4 * h;
    u32x4 tmp;
    tmp.x = lds[base]; tmp.y = lds[base + 1]; tmp.z = lds[base + 2]; tmp.w = lds[base + 3];
    g2 = MFMA(__builtin_bit_cast(bf16x8, tmp), ((const bf16x8*)g_bg2)[c * 64 + lane], g2);
  }

  // ---- o partials: stt part ----
  f32x16 o[5];
#pragma unroll
  for (int k = 0; k < 5; ++k)
#pragma unroll
    for (int r = 0; r < 16; ++r) o[k][r] = g2[r] * ht[k][r];

  // ---- ttt part: per-i gt GEMM + Wigner scatter ----
#pragma unroll
  for (int i = 0; i < 5; ++i) {
    f32x16 gt = zero16();
#pragma unroll
    for (int c = 0; c < 2; ++c) {
      int base = 2176 * (1 + i) + (wrow + wl) * 17 + c * 8 + 4 * h;
      u32x4 tmp;
      tmp.x = lds[base]; tmp.y = lds[base + 1]; tmp.z = lds[base + 2]; tmp.w = lds[base + 3];
      gt = MFMA(__builtin_bit_cast(bf16x8, tmp), ((const bf16x8*)g_bgt)[c * 64 + lane], gt);
    }
#pragma unroll
    for (int r = 0; r < 16; ++r) {
      float p0 = gt[r] * ht[0][r], p1 = gt[r] * ht[1][r], p2 = gt[r] * ht[2][r];
      float p3 = gt[r] * ht[3][r], p4 = gt[r] * ht[4][r];
      if (i == 0) {
        o[2][r] = fmaf(-CW1, p0, o[2][r]); o[3][r] = fmaf(CW2, p1, o[3][r]);
        o[0][r] = fmaf(-CW1, p2, o[0][r]); o[1][r] = fmaf(CW2, p3, o[1][r]);
      } else if (i == 1) {
        o[3][r] = fmaf(CW2, p0, o[3][r]);
        o[2][r] = fmaf(CW3, p1, o[2][r]); o[4][r] = fmaf(-CW2, p1, o[4][r]);
        o[1][r] = fmaf(CW3, p2, o[1][r]); o[0][r] = fmaf(CW2, p3, o[0][r]);
        o[1][r] = fmaf(-CW2, p4, o[1][r]);
      } else if (i == 2) {
        o[0][r] = fmaf(-CW1, p0, o[0][r]); o[1][r] = fmaf(CW3, p1, o[1][r]);
        o[2][r] = fmaf(CW1, p2, o[2][r]);  o[3][r] = fmaf(CW3, p3, o[3][r]);
        o[4][r] = fmaf(-CW1, p4, o[4][r]);
      } else if (i == 3) {
        o[1][r] = fmaf(CW2, p0, o[1][r]); o[0][r] = fmaf(CW2, p1, o[0][r]);
        o[3][r] = fmaf(CW3, p2, o[3][r]);
        o[2][r] = fmaf(CW3, p3, o[2][r]); o[4][r] = fmaf(CW2, p3, o[4][r]);
        o[3][r] = fmaf(CW2, p4, o[3][r]);
      } else {
        o[1][r] = fmaf(-CW2, p1, o[1][r]); o[4][r] = fmaf(-CW1, p2, o[4][r]);
        o[3][r] = fmaf(CW2, p3, o[3][r]);  o[2][r] = fmaf(-CW1, p4, o[2][r]);
      }
    }
  }

  // ---- butterfly reduce over the 32 lane-columns (v) within each half ----
#pragma unroll
  for (int m = 1; m <= 16; m <<= 1) {
#pragma unroll
    for (int k = 0; k < 5; ++k)
#pragma unroll
      for (int r = 0; r < 16; ++r) o[k][r] += __shfl_xor(o[k][r], m, 64);
  }

  // ---- direct stores: lanes with wl==k store plane k for their rows ----
#pragma unroll
  for (int k = 0; k < 5; ++k) {
    if (wl == k) {
#pragma unroll
      for (int r = 0; r < 16; ++r)
        out[(size_t)(rows128 + wrow + ROWP(r)) * 5 + k] = o[k][r];
    }
  }
}

extern "C" void kernel_launch(void* const* d_in, const int* in_sizes, int n_in,
                              void* d_out, int out_size, void* d_ws, size_t ws_size,
                              hipStream_t stream) {
  (void)n_in; (void)out_size; (void)d_ws; (void)ws_size;
  const float* scalars = (const float*)d_in[0];
  const float* tk  = (const float*)d_in[1];
  const float* tm  = (const float*)d_in[2];
  const float* tc  = (const float*)d_in[3];
  const float* tb  = (const float*)d_in[4];
  const float* tmc = (const float*)d_in[5];

  ech_prep<<<282, 256, 0, stream>>>((const float*)d_in[6], (const float*)d_in[7],
                                    (const float*)d_in[8], (const float*)d_in[9],
                                    (const float*)d_in[10], (const float*)d_in[11],
                                    (const float*)d_in[12], (const float*)d_in[13]);

  const int B = in_sizes[0] / 64;
  ech_fused<<<B / 128, 256, 0, stream>>>(scalars, tk, tm, tc, tb, tmc, (float*)d_out);
}

// Round 5
// 135.654 us; speedup vs baseline: 7.4255x; 1.2106x over previous
//
#include <hip/hip_runtime.h>
#include <math.h>
#include <stdint.h>

// ---------------------------------------------------------------------------
// EquivariantCorrectionHead, MFMA formulation v4.
// B=131072, NS=64, H=32. Block = 256 thr (4 waves), 128 batch rows/block.
// v4: triangular (symmetric) GEMM1, E/d stride 49 (bank-conflict-free),
// register diet (free ht after pack; j-outer o-phase) + launch_bounds(256,2).
// ---------------------------------------------------------------------------

#define CW1 0.23904572186687872f  // sqrt(2/35)
#define CW2 0.20701966780270626f  // sqrt(3/70)
#define CW3 0.11952286093343936f  // sqrt(1/70)

typedef float f32x16 __attribute__((ext_vector_type(16)));
typedef short bf16x8 __attribute__((ext_vector_type(8)));
typedef uint32_t u32x4 __attribute__((ext_vector_type(4)));

__device__ __forceinline__ uint32_t f2bf(float f) {  // RNE float->bf16
  uint32_t x = __float_as_uint(f);
  return (x + 0x7fffu + ((x >> 16) & 1u)) >> 16;
}
__device__ __forceinline__ uint32_t packbf(float lo, float hi) {
  return f2bf(lo) | (f2bf(hi) << 16);
}
__device__ __forceinline__ float bflo(uint32_t d) { return __uint_as_float(d << 16); }
__device__ __forceinline__ float bfhi(uint32_t d) { return __uint_as_float(d & 0xffff0000u); }

__device__ __forceinline__ f32x16 zero16() {
  f32x16 z;
#pragma unroll
  for (int i = 0; i < 16; ++i) z[i] = 0.f;
  return z;
}

#define MFMA(a, b, c) __builtin_amdgcn_mfma_f32_32x32x16_bf16((a), (b), (c), 0, 0, 0)

// Pre-swizzled bf16 B-fragment tables (dword = 2 packed bf16: k, k+1).
// Fragment convention: lane l (h=l>>5, col=l&31), dword d holds k=base+8h+2d, +1.
// g_bsss is SYMMETRIZED upper-triangular: entry (u,v) = W[u,v]+W[v,u] for u<v,
// W[u,u] on diag, 0 for u>v. Plane v only needs chunks c <= v/16.
__device__ __align__(16) uint32_t g_bsss[64 * 4 * 64 * 4];  // [v][c][l][d], k=u (K=64)
__device__ __align__(16) uint32_t g_bst[5 * 4 * 64 * 4];    // [v][c][l][d], k=u (K=64)
__device__ __align__(16) uint32_t g_btts[64 * 4];           // [l][d], k=p (K=16, p15 pad)
__device__ __align__(16) uint32_t g_bttt[64 * 4];           // [l][d]
__device__ __align__(16) uint32_t g_bg2[2 * 64 * 4];        // [c][l][d], k=u (K=32)
__device__ __align__(16) uint32_t g_bgt[2 * 64 * 4];        // [c][l][d]

__device__ const int c_pu[16] = {0,0,0,0,0,1,1,1,1,2,2,2,3,3,4,0};
__device__ const int c_pv[16] = {0,1,2,3,4,1,2,3,4,2,3,4,3,4,4,0};

__global__ void ech_prep(const float* __restrict__ w1_sss, const float* __restrict__ w1_stt,
                         const float* __restrict__ w1_tst, const float* __restrict__ w1_tts,
                         const float* __restrict__ w1_ttt, const float* __restrict__ w2_stt,
                         const float* __restrict__ w2_tst, const float* __restrict__ w2_ttt) {
  const float PW1_0 = (float)(1.0 / sqrt(4121.0));
  const float PW1_2 = (float)sqrt(5.0 / 665.0);
  const float PW2_2 = (float)sqrt(5.0 / 3072.0);
  const float IS5   = (float)sqrt(0.2);

  int idx = blockIdx.x * 256 + threadIdx.x;

  if (idx < 65536) {  // g_bsss (symmetrized triangular)
    int d = idx & 3, l = (idx >> 2) & 63, c = (idx >> 8) & 3, v = idx >> 10;
    int h = l >> 5, w = l & 31;
    int u0 = c * 16 + 8 * h + 2 * d, u1 = u0 + 1;
    float lo = 0.f, hi = 0.f;
    if (u0 < v)       lo = w1_sss[(u0 * 64 + v) * 32 + w] + w1_sss[(v * 64 + u0) * 32 + w];
    else if (u0 == v) lo = w1_sss[(u0 * 64 + v) * 32 + w];
    if (u1 < v)       hi = w1_sss[(u1 * 64 + v) * 32 + w] + w1_sss[(v * 64 + u1) * 32 + w];
    else if (u1 == v) hi = w1_sss[(u1 * 64 + v) * 32 + w];
    g_bsss[idx] = packbf(PW1_0 * lo, PW1_0 * hi);
    return;
  }
  idx -= 65536;
  if (idx < 5120) {  // g_bst
    int d = idx & 3, l = (idx >> 2) & 63, c = (idx >> 8) & 3, v = idx >> 10;
    int h = l >> 5, w = l & 31;
    float sc = PW1_2 * IS5;
    int u0 = c * 16 + 8 * h + 2 * d, u1 = u0 + 1;
    g_bst[idx] = packbf(sc * (w1_stt[(u0 * 5 + v) * 32 + w] + w1_tst[(v * 64 + u0) * 32 + w]),
                        sc * (w1_stt[(u1 * 5 + v) * 32 + w] + w1_tst[(v * 64 + u1) * 32 + w]));
    return;
  }
  idx -= 5120;
  if (idx < 256) {  // g_btts
    int d = idx & 3, l = idx >> 2;
    int h = l >> 5, w = l & 31;
    float sc = PW1_0 * IS5;
    float val[2];
#pragma unroll
    for (int q = 0; q < 2; ++q) {
      int p = 8 * h + 2 * d + q;
      float x = 0.f;
      if (p < 15) {
        int u = c_pu[p], v = c_pv[p];
        x = w1_tts[(u * 5 + v) * 32 + w];
        if (u < v) x += w1_tts[(v * 5 + u) * 32 + w];
        x *= sc;
      }
      val[q] = x;
    }
    g_btts[idx] = packbf(val[0], val[1]);
    return;
  }
  idx -= 256;
  if (idx < 256) {  // g_bttt
    int d = idx & 3, l = idx >> 2;
    int h = l >> 5, w = l & 31;
    float val[2];
#pragma unroll
    for (int q = 0; q < 2; ++q) {
      int p = 8 * h + 2 * d + q;
      float x = 0.f;
      if (p < 15) {
        int u = c_pu[p], v = c_pv[p];
        x = w1_ttt[(u * 5 + v) * 32 + w];
        if (u < v) x += w1_ttt[(v * 5 + u) * 32 + w];
        x *= PW1_2;
      }
      val[q] = x;
    }
    g_bttt[idx] = packbf(val[0], val[1]);
    return;
  }
  idx -= 256;
  if (idx < 512) {  // g_bg2: B[u][v] = (w2_stt[u,v]+w2_tst[v,u])*PW2_2*IS5
    int d = idx & 3, l = (idx >> 2) & 63, c = idx >> 8;
    int h = l >> 5, v = l & 31;
    float sc = PW2_2 * IS5;
    int u0 = c * 16 + 8 * h + 2 * d, u1 = u0 + 1;
    g_bg2[idx] = packbf(sc * (w2_stt[u0 * 32 + v] + w2_tst[v * 32 + u0]),
                        sc * (w2_stt[u1 * 32 + v] + w2_tst[v * 32 + u1]));
    return;
  }
  idx -= 512;
  if (idx < 512) {  // g_bgt: B[u][v] = w2_ttt[u,v]*PW2_2
    int d = idx & 3, l = (idx >> 2) & 63, c = idx >> 8;
    int h = l >> 5, v = l & 31;
    int u0 = c * 16 + 8 * h + 2 * d, u1 = u0 + 1;
    g_bgt[idx] = packbf(PW2_2 * w2_ttt[u0 * 32 + v], PW2_2 * w2_ttt[u1 * 32 + v]);
    return;
  }
}

// LDS layout (dwords), total 13696 dw = 54784 B:
//   s_packed bf16 [128][33]  @ 0      (dw 32 of each row = pad, never read)
//   t f32-bits    [128][25]  @ 4224
//   E/d bf16      [128][49]  @ 7424   (dword j of comp k at k*8+j; d at 40+j;
//                                      stride 49 => conflict-free frag reads)
// After the pack barrier (s/t/Ed dead): bf16 packs [128][17] per plane:
//   hs @ 0, ht_k @ 2176*(k+1), k=0..4 (ends 13056 <= 13696)
#define OFF_T 4224
#define OFF_ED 7424
#define ED_STRIDE 49
#define LDS_DW 13696

#define ROWP(r) (((r) & 3) + 8 * ((r) >> 2) + 4 * h)

__global__ __launch_bounds__(256, 2)
void ech_fused(const float* __restrict__ scalars,
               const float* __restrict__ tk, const float* __restrict__ tm,
               const float* __restrict__ tc, const float* __restrict__ tb,
               const float* __restrict__ tmc,
               float* __restrict__ out) {
  __shared__ uint32_t lds[LDS_DW];

  const int tid = threadIdx.x;
  const int rows128 = blockIdx.x * 128;
  const int wave = tid >> 6, lane = tid & 63;
  const int h = lane >> 5, wl = lane & 31;
  const int wrow = wave * 32;

  // ---- stage s (bf16-packed dwords) ----
#pragma unroll
  for (int it = 0; it < 16; ++it) {
    int di = it * 256 + tid;  // 4096 dwords
    int row = di >> 5, dw = di & 31;
    float f0 = scalars[(rows128 + row) * 64 + dw * 2];
    float f1 = scalars[(rows128 + row) * 64 + dw * 2 + 1];
    lds[row * 33 + dw] = packbf(f0, f1);
  }
  // ---- stage t (f32 bits as uint32) ----
#pragma unroll
  for (int v = 0; v < 5; ++v) {
    const float* p = (v == 0 ? tk : v == 1 ? tm : v == 2 ? tc : v == 3 ? tb : tmc);
#pragma unroll
    for (int it = 0; it < 3; ++it) {
      int i = it * 256 + tid;
      if (i < 640)
        lds[OFF_T + (i / 5) * 25 + v * 5 + (i % 5)] = __float_as_uint(p[rows128 * 5 + i]);
    }
  }
  __syncthreads();

  // ---- E/d phase: 2 threads per row, dword-granular ownership ----
  {
    int row = tid >> 1, part = tid & 1;
    float t_[5][5];
#pragma unroll
    for (int v = 0; v < 5; ++v)
#pragma unroll
      for (int k = 0; k < 5; ++k) t_[v][k] = __uint_as_float(lds[OFF_T + row * 25 + v * 5 + k]);

    float PA[6], PB[6];
#define EDP(U, V, OUT)                                                            \
  {                                                                               \
    float d0_ = t_[U][0] * t_[V][0], d1_ = t_[U][1] * t_[V][1];                   \
    float d2_ = t_[U][2] * t_[V][2], d3_ = t_[U][3] * t_[V][3];                   \
    float d4_ = t_[U][4] * t_[V][4];                                              \
    float s01_ = t_[U][0] * t_[V][1] + t_[U][1] * t_[V][0];                       \
    float s02_ = t_[U][0] * t_[V][2] + t_[U][2] * t_[V][0];                       \
    float s03_ = t_[U][0] * t_[V][3] + t_[U][3] * t_[V][0];                       \
    float s12_ = t_[U][1] * t_[V][2] + t_[U][2] * t_[V][1];                       \
    float s13_ = t_[U][1] * t_[V][3] + t_[U][3] * t_[V][1];                       \
    float s14_ = t_[U][1] * t_[V][4] + t_[U][4] * t_[V][1];                       \
    float s23_ = t_[U][2] * t_[V][3] + t_[U][3] * t_[V][2];                       \
    float s24_ = t_[U][2] * t_[V][4] + t_[U][4] * t_[V][2];                       \
    float s34_ = t_[U][3] * t_[V][4] + t_[U][4] * t_[V][3];                       \
    OUT[0] = -CW1 * s02_ + CW2 * s13_;                                            \
    OUT[1] = CW2 * s03_ + CW3 * s12_ - CW2 * s14_;                                \
    OUT[2] = -CW1 * d0_ + CW3 * d1_ + CW1 * d2_ + CW3 * d3_ - CW1 * d4_;          \
    OUT[3] = CW2 * s01_ + CW3 * s23_ + CW2 * s34_;                                \
    OUT[4] = -CW2 * d1_ - CW1 * s24_ + CW2 * d3_;                                 \
    OUT[5] = d0_ + d1_ + d2_ + d3_ + d4_;                                         \
  }
#define STEDP(j)                                                                  \
  {                                                                               \
    lds[rb + 0 * 8 + (j)] = packbf(PA[0], PB[0]);                                 \
    lds[rb + 1 * 8 + (j)] = packbf(PA[1], PB[1]);                                 \
    lds[rb + 2 * 8 + (j)] = packbf(PA[2], PB[2]);                                 \
    lds[rb + 3 * 8 + (j)] = packbf(PA[3], PB[3]);                                 \
    lds[rb + 4 * 8 + (j)] = packbf(PA[4], PB[4]);                                 \
    lds[rb + 40 + (j)] = packbf(PA[5], PB[5]);                                    \
  }
    int rb = OFF_ED + row * ED_STRIDE + (part ? 4 : 0);
    if (part == 0) {
      EDP(0, 0, PA) EDP(0, 1, PB) STEDP(0)
      EDP(0, 2, PA) EDP(0, 3, PB) STEDP(1)
      EDP(0, 4, PA) EDP(1, 1, PB) STEDP(2)
      EDP(1, 2, PA) EDP(1, 3, PB) STEDP(3)
    } else {
      EDP(1, 4, PA) EDP(2, 2, PB) STEDP(0)
      EDP(2, 3, PA) EDP(2, 4, PB) STEDP(1)
      EDP(3, 3, PA) EDP(3, 4, PB) STEDP(2)
      EDP(4, 4, PA)
#pragma unroll
      for (int q = 0; q < 6; ++q) PB[q] = 0.f;
      STEDP(3)
    }
#undef EDP
#undef STEDP
  }
  __syncthreads();

  // ---- A-fragments from LDS ----
  bf16x8 afr[4];
#pragma unroll
  for (int c = 0; c < 4; ++c) {
    int base = (wrow + wl) * 33 + c * 8 + 4 * h;
    u32x4 tmp;
    tmp.x = lds[base]; tmp.y = lds[base + 1]; tmp.z = lds[base + 2]; tmp.w = lds[base + 3];
    afr[c] = __builtin_bit_cast(bf16x8, tmp);
  }

  // ---- GEMM1 (sss, triangular): segment q needs chunks c<=q only ----
  f32x16 hs = zero16();
  const bf16x8* gb = (const bf16x8*)g_bsss;
#pragma unroll
  for (int q = 0; q < 4; ++q) {
#pragma unroll 2
    for (int vpi = 0; vpi < 8; ++vpi) {
      int vp = q * 8 + vpi;
      f32x16 Z0 = zero16(), Z1 = zero16();
#pragma unroll
      for (int c = 0; c <= q; ++c) {
        Z0 = MFMA(afr[c], gb[(2 * vp) * 256 + c * 64 + lane], Z0);
        Z1 = MFMA(afr[c], gb[(2 * vp + 1) * 256 + c * 64 + lane], Z1);
      }
#pragma unroll
      for (int r = 0; r < 16; ++r) {
        uint32_t d = lds[(wrow + ROWP(r)) * 33 + vp];  // broadcast read
        hs[r] = fmaf(bflo(d), Z0[r], hs[r]);
        hs[r] = fmaf(bfhi(d), Z1[r], hs[r]);
      }
    }
  }

  // ---- stt GEMM folded directly into ht ----
  f32x16 ht[5];
#pragma unroll
  for (int k = 0; k < 5; ++k) ht[k] = zero16();
  {
    const bf16x8* gs = (const bf16x8*)g_bst;
#pragma unroll
    for (int ct = 0; ct < 5; ++ct) {
      f32x16 acc = zero16();
#pragma unroll
      for (int c = 0; c < 4; ++c) acc = MFMA(afr[c], gs[(ct * 4 + c) * 64 + lane], acc);
#pragma unroll
      for (int r = 0; r < 16; ++r) {
        int row = wrow + ROWP(r);
        float av = acc[r];
#pragma unroll
        for (int k = 0; k < 5; ++k)
          ht[k][r] = fmaf(av, __uint_as_float(lds[OFF_T + row * 25 + ct * 5 + k]), ht[k][r]);
      }
    }
  }

  // ---- tts GEMM into hs ----
  {
    int base = OFF_ED + (wrow + wl) * ED_STRIDE + 40 + 4 * h;
    u32x4 tmp;
    tmp.x = lds[base]; tmp.y = lds[base + 1]; tmp.z = lds[base + 2]; tmp.w = lds[base + 3];
    hs = MFMA(__builtin_bit_cast(bf16x8, tmp), ((const bf16x8*)g_btts)[lane], hs);
  }
  // ---- ttt: per-k GEMM over pair-invariants ----
  {
    bf16x8 btt = ((const bf16x8*)g_bttt)[lane];
#pragma unroll
    for (int k = 0; k < 5; ++k) {
      int base = OFF_ED + (wrow + wl) * ED_STRIDE + k * 8 + 4 * h;
      u32x4 tmp;
      tmp.x = lds[base]; tmp.y = lds[base + 1]; tmp.z = lds[base + 2]; tmp.w = lds[base + 3];
      ht[k] = MFMA(__builtin_bit_cast(bf16x8, tmp), btt, ht[k]);
    }
  }

  // ---- pack hs + ht planes as bf16 dwords (ht registers die here) ----
  __syncthreads();  // s/t/Ed regions now dead
  {
#pragma unroll
    for (int r = 0; r < 16; ++r) {
      int row = wrow + ROWP(r);
      float v0 = hs[r];
      float pv = __shfl_xor(v0, 1, 64);
      if (!(wl & 1)) lds[row * 17 + (wl >> 1)] = packbf(v0, pv);
#pragma unroll
      for (int k = 0; k < 5; ++k) {
        float w0 = ht[k][r];
        float pw = __shfl_xor(w0, 1, 64);
        if (!(wl & 1)) lds[2176 * (k + 1) + row * 17 + (wl >> 1)] = packbf(w0, pw);
      }
    }
  }
  __syncthreads();

  // ---- g2 GEMM: g2[b,v] = hs @ w2c ----
  f32x16 g2 = zero16();
#pragma unroll
  for (int c = 0; c < 2; ++c) {
    int base = (wrow + wl) * 17 + c * 8 + 4 * h;
    u32x4 tmp;
    tmp.x = lds[base]; tmp.y = lds[base + 1]; tmp.z = lds[base + 2]; tmp.w = lds[base + 3];
    g2 = MFMA(__builtin_bit_cast(bf16x8, tmp), ((const bf16x8*)g_bg2)[c * 64 + lane], g2);
  }

  // ---- gt_i GEMMs (A-fragments from the ht pack; ht regs are free) ----
  f32x16 gt[5];
#pragma unroll
  for (int i = 0; i < 5; ++i) {
    f32x16 acc = zero16();
#pragma unroll
    for (int c = 0; c < 2; ++c) {
      int base = 2176 * (1 + i) + (wrow + wl) * 17 + c * 8 + 4 * h;
      u32x4 tmp;
      tmp.x = lds[base]; tmp.y = lds[base + 1]; tmp.z = lds[base + 2]; tmp.w = lds[base + 3];
      acc = MFMA(__builtin_bit_cast(bf16x8, tmp), ((const bf16x8*)g_bgt)[c * 64 + lane], acc);
    }
    gt[i] = acc;
  }

  // ---- o-phase, j-outer: re-read ht_j (bf16) from LDS; Wigner scatter ----
  f32x16 o[5];
#pragma unroll
  for (int k = 0; k < 5; ++k)
#pragma unroll
    for (int r = 0; r < 16; ++r) o[k][r] = 0.f;

#pragma unroll
  for (int j = 0; j < 5; ++j) {
#pragma unroll
    for (int r = 0; r < 16; ++r) {
      uint32_t dwv = lds[2176 * (j + 1) + (wrow + ROWP(r)) * 17 + (wl >> 1)];
      float hj = (wl & 1) ? bfhi(dwv) : bflo(dwv);
      float p0 = gt[0][r] * hj, p1 = gt[1][r] * hj, p2 = gt[2][r] * hj;
      float p3 = gt[3][r] * hj, p4 = gt[4][r] * hj;
      o[j][r] = fmaf(g2[r], hj, o[j][r]);
      if (j == 0) {
        o[2][r] = fmaf(-CW1, p0, o[2][r]); o[0][r] = fmaf(-CW1, p2, o[0][r]);
        o[3][r] = fmaf(CW2, p1, o[3][r]);  o[1][r] = fmaf(CW2, p3, o[1][r]);
      } else if (j == 1) {
        o[3][r] = fmaf(CW2, p0, o[3][r]);  o[0][r] = fmaf(CW2, p3, o[0][r]);
        o[2][r] = fmaf(CW3, p1, o[2][r]);  o[1][r] = fmaf(CW3, p2, o[1][r]);
        o[4][r] = fmaf(-CW2, p1, o[4][r]); o[1][r] = fmaf(-CW2, p4, o[1][r]);
      } else if (j == 2) {
        o[0][r] = fmaf(-CW1, p0, o[0][r]); o[1][r] = fmaf(CW3, p1, o[1][r]);
        o[2][r] = fmaf(CW1, p2, o[2][r]);  o[3][r] = fmaf(CW3, p3, o[3][r]);
        o[4][r] = fmaf(-CW1, p4, o[4][r]);
      } else if (j == 3) {
        o[1][r] = fmaf(CW2, p0, o[1][r]);  o[0][r] = fmaf(CW2, p1, o[0][r]);
        o[3][r] = fmaf(CW3, p2, o[3][r]);  o[2][r] = fmaf(CW3, p3, o[2][r]);
        o[4][r] = fmaf(CW2, p3, o[4][r]);  o[3][r] = fmaf(CW2, p4, o[3][r]);
      } else {
        o[1][r] = fmaf(-CW2, p1, o[1][r]); o[4][r] = fmaf(-CW1, p2, o[4][r]);
        o[2][r] = fmaf(-CW1, p4, o[2][r]); o[3][r] = fmaf(CW2, p3, o[3][r]);
      }
    }
  }

  // ---- butterfly reduce over the 32 lane-columns (v) within each half ----
#pragma unroll
  for (int m = 1; m <= 16; m <<= 1) {
#pragma unroll
    for (int k = 0; k < 5; ++k)
#pragma unroll
      for (int r = 0; r < 16; ++r) o[k][r] += __shfl_xor(o[k][r], m, 64);
  }

  // ---- direct stores: lanes with wl==k store plane k for their rows ----
#pragma unroll
  for (int k = 0; k < 5; ++k) {
    if (wl == k) {
#pragma unroll
      for (int r = 0; r < 16; ++r)
        out[(size_t)(rows128 + wrow + ROWP(r)) * 5 + k] = o[k][r];
    }
  }
}

extern "C" void kernel_launch(void* const* d_in, const int* in_sizes, int n_in,
                              void* d_out, int out_size, void* d_ws, size_t ws_size,
                              hipStream_t stream) {
  (void)n_in; (void)out_size; (void)d_ws; (void)ws_size;
  const float* scalars = (const float*)d_in[0];
  const float* tk  = (const float*)d_in[1];
  const float* tm  = (const float*)d_in[2];
  const float* tc  = (const float*)d_in[3];
  const float* tb  = (const float*)d_in[4];
  const float* tmc = (const float*)d_in[5];

  ech_prep<<<282, 256, 0, stream>>>((const float*)d_in[6], (const float*)d_in[7],
                                    (const float*)d_in[8], (const float*)d_in[9],
                                    (const float*)d_in[10], (const float*)d_in[11],
                                    (const float*)d_in[12], (const float*)d_in[13]);

  const int B = in_sizes[0] / 64;
  ech_fused<<<B / 128, 256, 0, stream>>>(scalars, tk, tm, tc, tb, tmc, (float*)d_out);
}